// Round 1
// baseline (141.199 us; speedup 1.0000x reference)
//
#include <hip/hip_runtime.h>
#include <math.h>

#define DIM   2048
#define NEXP  64
#define BM    64
#define BK    32
#define PAD   33   // 33-float rows: compute reads are <=2-way bank conflicts (free)

// Fused: logits GEMM (fp32 vector FMA) + softmax + top-2 + aux partial sums.
// Grid: n_tokens/BM = 256 blocks (1 per CU), 256 threads (4 waves).
__global__ __launch_bounds__(256)
void router_main(const float* __restrict__ x, const float* __restrict__ Wg,
                 float* __restrict__ out, float* __restrict__ gCnt,
                 float* __restrict__ gPsum, int n_tokens) {
    __shared__ float xs[2][BM][PAD];
    __shared__ float wsm[2][NEXP][PAD];
    __shared__ float ls[BM][NEXP + 1];
    __shared__ float cnt[NEXP];
    __shared__ float rs[BM];

    const int tid = threadIdx.x;
    const int t0  = blockIdx.x * BM;

    // staging mapping: row sr = tid>>2 (0..63), 8 consecutive floats at (tid&3)*8
    const int sr = tid >> 2;
    const int sq = (tid & 3) * 8;
    // compute mapping: 4 tokens x 4 experts per thread
    const int tt = tid >> 4;   // token quad 0..15
    const int ee = tid & 15;   // expert quad 0..15

    float acc[4][4];
#pragma unroll
    for (int i = 0; i < 4; ++i)
#pragma unroll
        for (int j = 0; j < 4; ++j) acc[i][j] = 0.f;

    const float* xrow = x  + (size_t)(t0 + sr) * DIM + sq;
    const float* wrow = Wg + (size_t)sr        * DIM + sq;

    // stage chunk 0
    {
        float4 xa = *(const float4*)(xrow);
        float4 xb = *(const float4*)(xrow + 4);
        float4 wa = *(const float4*)(wrow);
        float4 wb = *(const float4*)(wrow + 4);
#pragma unroll
        for (int j = 0; j < 4; ++j) {
            xs[0][sr][sq + j]     = ((const float*)&xa)[j];
            xs[0][sr][sq + 4 + j] = ((const float*)&xb)[j];
            wsm[0][sr][sq + j]     = ((const float*)&wa)[j];
            wsm[0][sr][sq + 4 + j] = ((const float*)&wb)[j];
        }
    }
    __syncthreads();

    const int nchunks = DIM / BK; // 64
    for (int c = 0; c < nchunks; ++c) {
        const int cur = c & 1;
        // prefetch next chunk into registers (hides HBM latency under compute)
        float4 pxa, pxb, pwa, pwb;
        const bool havenext = (c + 1 < nchunks);
        if (havenext) {
            const float* xp = xrow + (c + 1) * BK;
            const float* wp = wrow + (c + 1) * BK;
            pxa = *(const float4*)(xp);
            pxb = *(const float4*)(xp + 4);
            pwa = *(const float4*)(wp);
            pwb = *(const float4*)(wp + 4);
        }
        // compute current chunk: 4x4 register outer product
#pragma unroll
        for (int kk = 0; kk < BK; ++kk) {
            float xv[4], wv[4];
#pragma unroll
            for (int i = 0; i < 4; ++i) xv[i] = xs[cur][tt * 4 + i][kk];
#pragma unroll
            for (int j = 0; j < 4; ++j) wv[j] = wsm[cur][ee * 4 + j][kk];
#pragma unroll
            for (int i = 0; i < 4; ++i)
#pragma unroll
                for (int j = 0; j < 4; ++j) acc[i][j] = fmaf(xv[i], wv[j], acc[i][j]);
        }
        if (havenext) {
            const int nxt = cur ^ 1;
#pragma unroll
            for (int j = 0; j < 4; ++j) {
                xs[nxt][sr][sq + j]     = ((const float*)&pxa)[j];
                xs[nxt][sr][sq + 4 + j] = ((const float*)&pxb)[j];
                wsm[nxt][sr][sq + j]     = ((const float*)&pwa)[j];
                wsm[nxt][sr][sq + 4 + j] = ((const float*)&pwb)[j];
            }
        }
        __syncthreads();
    }

    // scatter logits to LDS
#pragma unroll
    for (int i = 0; i < 4; ++i)
#pragma unroll
        for (int j = 0; j < 4; ++j)
            ls[tt * 4 + i][ee * 4 + j] = acc[i][j];
    if (tid < NEXP) cnt[tid] = 0.f;
    __syncthreads();

    // per-token: softmax + top-2 + outputs (thread t handles token t)
    if (tid < BM) {
        const int t = tid;
        float m1 = -1e30f, m2 = -1e30f;
        int i1 = 0, i2 = 0;
#pragma unroll
        for (int e = 0; e < NEXP; ++e) {
            float l = ls[t][e];
            if (l > m1)      { m2 = m1; i2 = i1; m1 = l; i1 = e; }
            else if (l > m2) { m2 = l; i2 = e; }
        }
        float s = 0.f;
#pragma unroll
        for (int e = 0; e < NEXP; ++e) {
            float p = __expf(ls[t][e] - m1);
            ls[t][e] = p;   // store unnormalized probs for column sums
            s += p;
        }
        const float inv_s = 1.f / s;
        rs[t] = inv_s;
        const float r1 = inv_s;                       // exp(m1-m1)=1
        const float r2 = __expf(m2 - m1) * inv_s;
        const float denom = r1 + r2 + 1e-8f;
        const int tg = t0 + t;
        out[(size_t)tg * 2]     = (float)i1;
        out[(size_t)tg * 2 + 1] = (float)i2;
        out[(size_t)n_tokens * 2 + (size_t)tg * 2]     = r1 / denom;
        out[(size_t)n_tokens * 2 + (size_t)tg * 2 + 1] = r2 / denom;
        atomicAdd(&cnt[i1], 1.f);
        atomicAdd(&cnt[i2], 1.f);
    }
    __syncthreads();

    // per-expert column sums of router_probs + global accumulation
    if (tid < NEXP) {
        float cs = 0.f;
#pragma unroll
        for (int t = 0; t < BM; ++t) cs += ls[t][tid] * rs[t];
        atomicAdd(&gPsum[tid], cs);
        atomicAdd(&gCnt[tid], cnt[tid]);
    }
}

__global__ void router_aux(const float* __restrict__ gCnt,
                           const float* __restrict__ gPsum,
                           float* __restrict__ out, int n_tokens) {
    const int e = threadIdx.x; // 64 threads = 1 wave
    float f = gCnt[e] / (float)(n_tokens * 2);
    float P = gPsum[e] / (float)n_tokens;
    float v = f * P;
#pragma unroll
    for (int o = 32; o > 0; o >>= 1) v += __shfl_down(v, o);
    if (e == 0) out[(size_t)n_tokens * 4] = 64.f * v;
}

extern "C" void kernel_launch(void* const* d_in, const int* in_sizes, int n_in,
                              void* d_out, int out_size, void* d_ws, size_t ws_size,
                              hipStream_t stream) {
    const float* x  = (const float*)d_in[0];
    const float* Wg = (const float*)d_in[1];
    float* out = (float*)d_out;
    const int n_tokens = in_sizes[0] / DIM;   // 16384
    float* gCnt  = (float*)d_ws;
    float* gPsum = gCnt + NEXP;
    hipMemsetAsync(d_ws, 0, 2 * NEXP * sizeof(float), stream);
    hipLaunchKernelGGL(router_main, dim3(n_tokens / BM), dim3(256), 0, stream,
                       x, Wg, out, gCnt, gPsum, n_tokens);
    hipLaunchKernelGGL(router_aux, dim3(1), dim3(NEXP), 0, stream,
                       gCnt, gPsum, out, n_tokens);
}

// Round 2
// 86.940 us; speedup vs baseline: 1.6241x; 1.6241x over previous
//
#include <hip/hip_runtime.h>
#include <math.h>

#define DIM    2048
#define NEXP   64
#define BM     64
#define BK     32
#define KS     2
#define KC     (DIM / KS)      // 1024 K per block
#define NCH    (KC / BK)       // 32 chunks
#define XST    68              // LDS row stride (floats): 16B-aligned, bank-spread

// ---------------- Kernel 1: partial logits GEMM (fp32 vector FMA) -----------
// grid = 256 token-blocks * KS, block = 256 threads (4 waves).
// LDS tiles stored TRANSPOSED [K][M] so the inner loop reads are ds_read_b128.
__global__ __launch_bounds__(256)
void router_part(const float* __restrict__ x, const float* __restrict__ Wg,
                 float* __restrict__ part, int n_tokens) {
    __shared__ float xs[2][BK][XST];
    __shared__ float wsm[2][BK][XST];

    const int tid = threadIdx.x;
    const int tb  = blockIdx.x & 255;     // token block
    const int ks  = blockIdx.x >> 8;      // K-split index
    const int t0  = tb * BM;
    const int k0  = ks * KC;

    const int sr = tid >> 2;              // staged row 0..63
    const int sq = (tid & 3) * 8;         // 8-float segment within BK=32
    const int tt = tid >> 4;              // token quad 0..15
    const int ee = tid & 15;              // expert quad 0..15

    float acc[4][4];
#pragma unroll
    for (int i = 0; i < 4; ++i)
#pragma unroll
        for (int j = 0; j < 4; ++j) acc[i][j] = 0.f;

    const float* xrow = x  + (size_t)(t0 + sr) * DIM + k0 + sq;
    const float* wrow = Wg + (size_t)sr        * DIM + k0 + sq;

    // stage chunk 0 (transposed scatter: 8 scalar LDS writes per array)
    {
        float4 xa = *(const float4*)(xrow);
        float4 xb = *(const float4*)(xrow + 4);
        float4 wa = *(const float4*)(wrow);
        float4 wb = *(const float4*)(wrow + 4);
#pragma unroll
        for (int j = 0; j < 4; ++j) {
            xs [0][sq + j][sr]     = ((const float*)&xa)[j];
            xs [0][sq + 4 + j][sr] = ((const float*)&xb)[j];
            wsm[0][sq + j][sr]     = ((const float*)&wa)[j];
            wsm[0][sq + 4 + j][sr] = ((const float*)&wb)[j];
        }
    }
    __syncthreads();

    for (int c = 0; c < NCH; ++c) {
        const int cur = c & 1;
        float4 pxa, pxb, pwa, pwb;
        const bool nx = (c + 1 < NCH);
        if (nx) {
            const float* xp = xrow + (c + 1) * BK;
            const float* wp = wrow + (c + 1) * BK;
            pxa = *(const float4*)(xp);
            pxb = *(const float4*)(xp + 4);
            pwa = *(const float4*)(wp);
            pwb = *(const float4*)(wp + 4);
        }
        // inner loop: 2x ds_read_b128 + 16 FMA per kk
#pragma unroll
        for (int kk = 0; kk < BK; ++kk) {
            float4 xv = *(const float4*)&xs [cur][kk][tt * 4];
            float4 wv = *(const float4*)&wsm[cur][kk][ee * 4];
            const float* xvf = (const float*)&xv;
            const float* wvf = (const float*)&wv;
#pragma unroll
            for (int i = 0; i < 4; ++i)
#pragma unroll
                for (int j = 0; j < 4; ++j)
                    acc[i][j] = fmaf(xvf[i], wvf[j], acc[i][j]);
        }
        if (nx) {
            const int nxt = cur ^ 1;
#pragma unroll
            for (int j = 0; j < 4; ++j) {
                xs [nxt][sq + j][sr]     = ((const float*)&pxa)[j];
                xs [nxt][sq + 4 + j][sr] = ((const float*)&pxb)[j];
                wsm[nxt][sq + j][sr]     = ((const float*)&pwa)[j];
                wsm[nxt][sq + 4 + j][sr] = ((const float*)&pwb)[j];
            }
        }
        __syncthreads();
    }

    // write partial logits: part[ks][token][expert], float4 coalesced
    float* pb = part + ((size_t)ks * n_tokens + t0) * NEXP;
#pragma unroll
    for (int i = 0; i < 4; ++i) {
        float4 v;
        v.x = acc[i][0]; v.y = acc[i][1]; v.z = acc[i][2]; v.w = acc[i][3];
        *(float4*)&pb[(size_t)(tt * 4 + i) * NEXP + ee * 4] = v;
    }
}

// ---------------- Kernel 2: reduce partials + softmax + top-2 + aux ---------
__global__ __launch_bounds__(256)
void router_finish(const float* __restrict__ part, float* __restrict__ out,
                   float* __restrict__ gCnt, float* __restrict__ gPsum,
                   int n_tokens) {
    __shared__ float pl[256][NEXP + 1];
    __shared__ float cnt[NEXP];
    const int tid = threadIdx.x;
    const int tok = blockIdx.x * 256 + tid;

    if (tid < NEXP) cnt[tid] = 0.f;

    float lg[NEXP];
#pragma unroll
    for (int q = 0; q < NEXP / 4; ++q) {
        float4 a = *(const float4*)&part[(size_t)tok * NEXP + q * 4];
        float4 b = *(const float4*)&part[((size_t)n_tokens + tok) * NEXP + q * 4];
        lg[q * 4 + 0] = a.x + b.x;
        lg[q * 4 + 1] = a.y + b.y;
        lg[q * 4 + 2] = a.z + b.z;
        lg[q * 4 + 3] = a.w + b.w;
    }

    // top-2 (strict > keeps lowest index on ties, matching lax.top_k)
    float m1 = -1e30f, m2 = -1e30f;
    int i1 = 0, i2 = 0;
#pragma unroll
    for (int e = 0; e < NEXP; ++e) {
        float l = lg[e];
        if (l > m1)      { m2 = m1; i2 = i1; m1 = l; i1 = e; }
        else if (l > m2) { m2 = l; i2 = e; }
    }

    float s = 0.f;
#pragma unroll
    for (int e = 0; e < NEXP; ++e) {
        float p = __expf(lg[e] - m1);
        lg[e] = p;
        s += p;
    }
    const float inv_s = 1.f / s;
#pragma unroll
    for (int e = 0; e < NEXP; ++e) pl[tid][e] = lg[e] * inv_s;

    const float p1 = inv_s;                       // exp(0)/s
    const float p2 = __expf(m2 - m1) * inv_s;
    const float d  = p1 + p2 + 1e-8f;
    out[(size_t)tok * 2]     = (float)i1;
    out[(size_t)tok * 2 + 1] = (float)i2;
    out[(size_t)n_tokens * 2 + (size_t)tok * 2]     = p1 / d;
    out[(size_t)n_tokens * 2 + (size_t)tok * 2 + 1] = p2 / d;
    atomicAdd(&cnt[i1], 1.f);
    atomicAdd(&cnt[i2], 1.f);
    __syncthreads();

    if (tid < NEXP) {
        float cs = 0.f;
#pragma unroll 8
        for (int t = 0; t < 256; ++t) cs += pl[t][tid];
        atomicAdd(&gPsum[tid], cs);
        atomicAdd(&gCnt[tid], cnt[tid]);
    }
}

// ---------------- Kernel 3: final aux loss ----------------------------------
__global__ void router_aux(const float* __restrict__ gCnt,
                           const float* __restrict__ gPsum,
                           float* __restrict__ out, int n_tokens) {
    const int e = threadIdx.x; // 64 threads = 1 wave
    float f = gCnt[e] / (float)(n_tokens * 2);
    float P = gPsum[e] / (float)n_tokens;
    float v = f * P;
#pragma unroll
    for (int o = 32; o > 0; o >>= 1) v += __shfl_down(v, o);
    if (e == 0) out[(size_t)n_tokens * 4] = 64.f * v;
}

extern "C" void kernel_launch(void* const* d_in, const int* in_sizes, int n_in,
                              void* d_out, int out_size, void* d_ws, size_t ws_size,
                              hipStream_t stream) {
    const float* x  = (const float*)d_in[0];
    const float* Wg = (const float*)d_in[1];
    float* out = (float*)d_out;
    const int n_tokens = in_sizes[0] / DIM;   // 16384

    float* gCnt  = (float*)d_ws;
    float* gPsum = gCnt + NEXP;
    float* part  = gPsum + NEXP;              // KS * n_tokens * NEXP floats

    hipMemsetAsync(d_ws, 0, 2 * NEXP * sizeof(float), stream);
    hipLaunchKernelGGL(router_part, dim3((n_tokens / BM) * KS), dim3(256), 0, stream,
                       x, Wg, part, n_tokens);
    hipLaunchKernelGGL(router_finish, dim3(n_tokens / 256), dim3(256), 0, stream,
                       part, out, gCnt, gPsum, n_tokens);
    hipLaunchKernelGGL(router_aux, dim3(1), dim3(NEXP), 0, stream,
                       gCnt, gPsum, out, n_tokens);
}